// Round 9
// baseline (957.781 us; speedup 1.0000x reference)
//
#include <hip/hip_runtime.h>

#define S 4096
#define D 64
#define NB 16

typedef _Float16 half8 __attribute__((ext_vector_type(8)));
typedef _Float16 half2v __attribute__((ext_vector_type(2)));
typedef float f32x4 __attribute__((ext_vector_type(4)));
typedef int int4v __attribute__((ext_vector_type(4)));

// ---- Prepass A: Q (scaled by 1/8) and K -> fp16 ----
__global__ void cvt_qk(const float* __restrict__ Q, const float* __restrict__ K,
                       _Float16* __restrict__ Qh, _Float16* __restrict__ Kh, int n) {
  int i = blockIdx.x * blockDim.x + threadIdx.x;
  int stride = gridDim.x * blockDim.x;
  for (; i < n; i += stride) {
    Qh[i] = (_Float16)(Q[i] * 0.125f);   // fold 1/TEMPERATURE into Q
    Kh[i] = (_Float16)(K[i]);
  }
}

// ---- Prepass B: V -> fp16 transposed Vt[b][d][s] ----
__global__ void cvt_vt(const float* __restrict__ V, _Float16* __restrict__ Vt) {
  __shared__ float tile[64][65];
  int b = blockIdx.x >> 6;
  int s0 = (blockIdx.x & 63) * 64;
  const float* vb = V + ((size_t)b * S) * D;
  for (int i = threadIdx.x; i < 64 * 64; i += 256) {
    int sl = i >> 6, d = i & 63;
    tile[sl][d] = vb[(size_t)(s0 + sl) * D + d];
  }
  __syncthreads();
  _Float16* vtb = Vt + ((size_t)b * D) * S;
  for (int i = threadIdx.x; i < 64 * 64; i += 256) {
    int dl = i >> 6, sl = i & 63;
    vtb[(size_t)dl * S + s0 + sl] = (_Float16)tile[sl][dl];
  }
}

// ---- Pass 1: X = softmax(QK^T)V and Lsum = log(rowsum(exp)) ----
// Rolled 16-step loop (32 keys/step) with explicit depth-1 K prefetch.
// Cross-round evidence: store/load BW scales linearly with waves (per-wave
// serialization on exposed load latency); fully-unrolled loops let the
// allocator emit vmcnt(0) per iteration. Structural prefetch breaks that.
// Swapped QK^T + shfl transpose kept verbatim from R8 (numerically proven).
__global__ __launch_bounds__(512, 2) void attn_pv(
    const _Float16* __restrict__ Qh, const _Float16* __restrict__ Kh,
    const _Float16* __restrict__ Vt, float* __restrict__ X, float* __restrict__ Lsum) {
  const int tid = threadIdx.x;
  const int w = tid >> 6;
  const int l = tid & 63;
  const int l15 = l & 15;
  const int lq = l >> 4;
  const int r4 = lq * 4;
  const int bx = blockIdx.x;
  const int b = bx >> 8;
  const int m0 = (bx & 255) * 16;

  const _Float16* qb = Qh + ((size_t)b * S + m0) * D;
  const _Float16* kb = Kh + ((size_t)b * S) * D;
  const _Float16* vtb = Vt + ((size_t)b * D) * S;

  __shared__ float lred[8][16];
  __shared__ __align__(16) float xred[8][16][66];

  half8 qf0 = *(const half8*)(qb + (size_t)l15 * D + lq * 8);
  half8 qf1 = *(const half8*)(qb + (size_t)l15 * D + 32 + lq * 8);

  const int nbase = w * 512;
  const int srcA = (lq & 1) * 32 + l15;
  const int srcB = srcA + 16;
  const bool hi = (lq & 2) != 0;

  // K base for this lane: row (nbase + l15), col lq*8; step stride 32 rows
  const _Float16* kp0 = kb + (size_t)(nbase + l15) * D + lq * 8;
  const _Float16* vp0 = vtb + (size_t)l15 * S + nbase + lq * 8;

  float vsum = 0.f;
  f32x4 xacc[4];
#pragma unroll
  for (int fd = 0; fd < 4; ++fd) xacc[fd] = (f32x4){0.f, 0.f, 0.f, 0.f};

  // prologue: prefetch step-0 t0 K pair
  half8 kc0 = *(const half8*)(kp0);
  half8 kc1 = *(const half8*)(kp0 + 32);

#pragma unroll 1
  for (int s = 0; s < 16; ++s) {
    // issue this step's independent loads first: V(4) + t1 K pair
    const _Float16* vs = vp0 + s * 32;
    half8 bf0 = *(const half8*)(vs);
    half8 bf1 = *(const half8*)(vs + 16 * S);
    half8 bf2 = *(const half8*)(vs + 32 * S);
    half8 bf3 = *(const half8*)(vs + 48 * S);
    const _Float16* k1p = kp0 + (size_t)(s * 32 + 16) * D;
    half8 k10 = *(const half8*)(k1p);
    half8 k11 = *(const half8*)(k1p + 32);
    // prefetch next step's t0 K pair
    half8 kn0 = kc0, kn1 = kc1;
    if (s < 15) {
      const _Float16* knp = kp0 + (size_t)((s + 1) * 32) * D;
      kn0 = *(const half8*)(knp);
      kn1 = *(const half8*)(knp + 32);
    }
    // t0: QK^T (prefetched K ready) -> exp -> pack
    f32x4 a0 = (f32x4){0.f, 0.f, 0.f, 0.f};
    a0 = __builtin_amdgcn_mfma_f32_16x16x32_f16(kc0, qf0, a0, 0, 0, 0);
    a0 = __builtin_amdgcn_mfma_f32_16x16x32_f16(kc1, qf1, a0, 0, 0, 0);
    float p0 = __expf(a0[0]), p1 = __expf(a0[1]);
    float p2 = __expf(a0[2]), p3 = __expf(a0[3]);
    vsum += (p0 + p1) + (p2 + p3);
    half2v h01 = {(_Float16)p0, (_Float16)p1};
    half2v h23 = {(_Float16)p2, (_Float16)p3};
    int dw0x = __builtin_bit_cast(int, h01);
    int dw0y = __builtin_bit_cast(int, h23);
    // t1
    f32x4 a1 = (f32x4){0.f, 0.f, 0.f, 0.f};
    a1 = __builtin_amdgcn_mfma_f32_16x16x32_f16(k10, qf0, a1, 0, 0, 0);
    a1 = __builtin_amdgcn_mfma_f32_16x16x32_f16(k11, qf1, a1, 0, 0, 0);
    float q0 = __expf(a1[0]), q1 = __expf(a1[1]);
    float q2 = __expf(a1[2]), q3 = __expf(a1[3]);
    vsum += (q0 + q1) + (q2 + q3);
    half2v g01 = {(_Float16)q0, (_Float16)q1};
    half2v g23 = {(_Float16)q2, (_Float16)q3};
    int dw1x = __builtin_bit_cast(int, g01);
    int dw1y = __builtin_bit_cast(int, g23);
    // shfl transpose -> PV A-frag (verbatim R8)
    int yA0 = __shfl(dw0x, srcA, 64), yA1 = __shfl(dw0y, srcA, 64);
    int yB0 = __shfl(dw0x, srcB, 64), yB1 = __shfl(dw0y, srcB, 64);
    int xA0 = __shfl(dw1x, srcA, 64), xA1 = __shfl(dw1y, srcA, 64);
    int xB0 = __shfl(dw1x, srcB, 64), xB1 = __shfl(dw1y, srcB, 64);
    int4v ai = {hi ? xA0 : yA0, hi ? xA1 : yA1, hi ? xB0 : yB0, hi ? xB1 : yB1};
    half8 af = __builtin_bit_cast(half8, ai);
    // PV
    xacc[0] = __builtin_amdgcn_mfma_f32_16x16x32_f16(af, bf0, xacc[0], 0, 0, 0);
    xacc[1] = __builtin_amdgcn_mfma_f32_16x16x32_f16(af, bf1, xacc[1], 0, 0, 0);
    xacc[2] = __builtin_amdgcn_mfma_f32_16x16x32_f16(af, bf2, xacc[2], 0, 0, 0);
    xacc[3] = __builtin_amdgcn_mfma_f32_16x16x32_f16(af, bf3, xacc[3], 0, 0, 0);
    // rotate prefetch
    kc0 = kn0;
    kc1 = kn1;
  }

  // row sums across the 4 lq-lanes sharing query l15
  vsum += __shfl_xor(vsum, 16, 64);
  vsum += __shfl_xor(vsum, 32, 64);
  if (l < 16) lred[w][l] = vsum;
  __syncthreads();

  if (tid < 16) {
    float s = 0.f;
#pragma unroll
    for (int ww = 0; ww < 8; ++ww) s += lred[ww][tid];
    Lsum[(size_t)b * S + m0 + tid] = __logf(s);
  }

  float rinvX[4];
#pragma unroll
  for (int j = 0; j < 4; ++j) {
    float s = 0.f;
#pragma unroll
    for (int ww = 0; ww < 8; ++ww) s += lred[ww][r4 + j];
    rinvX[j] = 1.0f / s;
  }

  // cross-wave reduce of X (xacc: X[q=r4+j][d=fd*16+l15])
#pragma unroll
  for (int fd = 0; fd < 4; ++fd)
#pragma unroll
    for (int j = 0; j < 4; ++j)
      xred[w][r4 + j][fd * 16 + l15] = xacc[fd][j] * rinvX[j];
  __syncthreads();
  float* xrow = X + ((size_t)b * S + m0) * D;
#pragma unroll
  for (int o = tid; o < 16 * 64; o += 512) {
    int r = o >> 6, d = o & 63;
    float s = 0.f;
#pragma unroll
    for (int ww = 0; ww < 8; ++ww) s += xred[ww][r][d];
    xrow[(size_t)r * D + d] = s;
  }
}

// ---- Pass 2: A store. Rolled 32-step loop (16 keys/step), depth-1 K
// prefetch, zero LDS, zero fences, ~48 live regs -> (512,4) spill-free at
// 32 waves/CU. p = exp(score - lsum) stored directly normalized. ----
__global__ __launch_bounds__(512, 4) void attn_store(
    const _Float16* __restrict__ Qh, const _Float16* __restrict__ Kh,
    const float* __restrict__ Lsum, float* __restrict__ Aout) {
  const int tid = threadIdx.x;
  const int w = tid >> 6;
  const int l = tid & 63;
  const int l15 = l & 15;
  const int lq = l >> 4;
  const int r4 = lq * 4;
  const int bx = blockIdx.x;
  const int b = bx >> 8;
  const int m0 = (bx & 255) * 16;

  const _Float16* qb = Qh + ((size_t)b * S + m0) * D;
  const _Float16* kb = Kh + ((size_t)b * S) * D;

  half8 qf0 = *(const half8*)(qb + (size_t)l15 * D + lq * 8);
  half8 qf1 = *(const half8*)(qb + (size_t)l15 * D + 32 + lq * 8);

  const float ls = Lsum[(size_t)b * S + m0 + l15];
  const int nbase = w * 512;
  const _Float16* kp0 = kb + (size_t)(nbase + l15) * D + lq * 8;  // step stride 16*D
  float* arow = Aout + ((size_t)(b * S + m0 + l15)) * S + nbase + r4;

  half8 c0 = *(const half8*)(kp0);
  half8 c1 = *(const half8*)(kp0 + 32);

#pragma unroll 1
  for (int s = 0; s < 32; ++s) {
    half8 n0 = c0, n1 = c1;
    if (s < 31) {
      const _Float16* np = kp0 + (size_t)(s + 1) * (16 * D);
      n0 = *(const half8*)(np);
      n1 = *(const half8*)(np + 32);
    }
    f32x4 a = (f32x4){0.f, 0.f, 0.f, 0.f};
    a = __builtin_amdgcn_mfma_f32_16x16x32_f16(c0, qf0, a, 0, 0, 0);
    a = __builtin_amdgcn_mfma_f32_16x16x32_f16(c1, qf1, a, 0, 0, 0);
    f32x4 o;
#pragma unroll
    for (int j = 0; j < 4; ++j) o[j] = __expf(a[j] - ls);
    *(f32x4*)(arow + s * 16) = o;
    c0 = n0;
    c1 = n1;
  }
}

extern "C" void kernel_launch(void* const* d_in, const int* in_sizes, int n_in,
                              void* d_out, int out_size, void* d_ws, size_t ws_size,
                              hipStream_t stream) {
  const float* Q = (const float*)d_in[0];
  const float* K = (const float*)d_in[1];
  const float* V = (const float*)d_in[2];
  float* X = (float*)d_out;                       // [16,4096,64]
  float* A = X + (size_t)NB * S * D;              // [16,4096,4096]
  _Float16* Qh = (_Float16*)d_ws;
  _Float16* Kh = Qh + (size_t)NB * S * D;
  _Float16* Vt = Kh + (size_t)NB * S * D;
  float* Lsum = (float*)(Vt + (size_t)NB * S * D);  // [16,4096] f32
  int n = NB * S * D;
  cvt_qk<<<2048, 256, 0, stream>>>(Q, K, Qh, Kh, n);
  cvt_vt<<<NB * 64, 256, 0, stream>>>(V, Vt);
  attn_pv<<<NB * 256, 512, 0, stream>>>(Qh, Kh, Vt, X, Lsum);
  attn_store<<<NB * 256, 512, 0, stream>>>(Qh, Kh, Lsum, A);
}

// Round 10
// 828.445 us; speedup vs baseline: 1.1561x; 1.1561x over previous
//
#include <hip/hip_runtime.h>

#define S 4096
#define D 64
#define NB 16

typedef _Float16 half8 __attribute__((ext_vector_type(8)));
typedef _Float16 half2v __attribute__((ext_vector_type(2)));
typedef float f32x4 __attribute__((ext_vector_type(4)));
typedef int int4v __attribute__((ext_vector_type(4)));

// ---- Prepass A: Q (scaled by 1/8) and K -> fp16 ----
__global__ void cvt_qk(const float* __restrict__ Q, const float* __restrict__ K,
                       _Float16* __restrict__ Qh, _Float16* __restrict__ Kh, int n) {
  int i = blockIdx.x * blockDim.x + threadIdx.x;
  int stride = gridDim.x * blockDim.x;
  for (; i < n; i += stride) {
    Qh[i] = (_Float16)(Q[i] * 0.125f);   // fold 1/TEMPERATURE into Q
    Kh[i] = (_Float16)(K[i]);
  }
}

// ---- Prepass B: V -> fp16 transposed Vt[b][d][s] ----
__global__ void cvt_vt(const float* __restrict__ V, _Float16* __restrict__ Vt) {
  __shared__ float tile[64][65];
  int b = blockIdx.x >> 6;
  int s0 = (blockIdx.x & 63) * 64;
  const float* vb = V + ((size_t)b * S) * D;
  for (int i = threadIdx.x; i < 64 * 64; i += 256) {
    int sl = i >> 6, d = i & 63;
    tile[sl][d] = vb[(size_t)(s0 + sl) * D + d];
  }
  __syncthreads();
  _Float16* vtb = Vt + ((size_t)b * D) * S;
  for (int i = threadIdx.x; i < 64 * 64; i += 256) {
    int dl = i >> 6, sl = i & 63;
    vtb[(size_t)dl * S + s0 + sl] = (_Float16)tile[sl][dl];
  }
}

// ---- Pass 1 (small): Lsum = log(rowsum(exp(QK^T/8))) ----
// Swapped QK^T, rolled 32x16-key steps, depth-2 K prefetch, ~45 regs,
// (512,4) [blocks/CU semantics] -> 32 waves/CU. Pure L2-read + MFMA + exp.
__global__ __launch_bounds__(512, 4) void attn_lsum(
    const _Float16* __restrict__ Qh, const _Float16* __restrict__ Kh,
    float* __restrict__ Lsum) {
  const int tid = threadIdx.x;
  const int w = tid >> 6;
  const int l = tid & 63;
  const int l15 = l & 15;
  const int lq = l >> 4;
  const int bx = blockIdx.x;
  const int b = bx >> 8;
  const int m0 = (bx & 255) * 16;

  const _Float16* qb = Qh + ((size_t)b * S + m0) * D;
  const _Float16* kb = Kh + ((size_t)b * S) * D;

  __shared__ float lred[8][16];

  half8 qf0 = *(const half8*)(qb + (size_t)l15 * D + lq * 8);
  half8 qf1 = *(const half8*)(qb + (size_t)l15 * D + 32 + lq * 8);

  const int nbase = w * 512;
  const _Float16* kp0 = kb + (size_t)(nbase + l15) * D + lq * 8;

  half8 kc0 = *(const half8*)(kp0);
  half8 kc1 = *(const half8*)(kp0 + 32);
  half8 kn0 = *(const half8*)(kp0 + (size_t)16 * D);
  half8 kn1 = *(const half8*)(kp0 + (size_t)16 * D + 32);

  float vsum = 0.f;
#pragma unroll 1
  for (int s = 0; s < 32; ++s) {
    half8 km0 = kc0, km1 = kc1;
    if (s < 30) {
      const _Float16* kp = kp0 + (size_t)((s + 2) * 16) * D;
      km0 = *(const half8*)(kp);
      km1 = *(const half8*)(kp + 32);
    }
    f32x4 a = (f32x4){0.f, 0.f, 0.f, 0.f};
    a = __builtin_amdgcn_mfma_f32_16x16x32_f16(kc0, qf0, a, 0, 0, 0);
    a = __builtin_amdgcn_mfma_f32_16x16x32_f16(kc1, qf1, a, 0, 0, 0);
    vsum += (__expf(a[0]) + __expf(a[1])) + (__expf(a[2]) + __expf(a[3]));
    kc0 = kn0; kc1 = kn1;
    kn0 = km0; kn1 = km1;
  }

  // reduce over the 4 lq-lanes sharing query l15, then across waves
  vsum += __shfl_xor(vsum, 16, 64);
  vsum += __shfl_xor(vsum, 32, 64);
  if (l < 16) lred[w][l] = vsum;
  __syncthreads();
  if (tid < 16) {
    float s = 0.f;
#pragma unroll
    for (int ww = 0; ww < 8; ++ww) s += lred[ww][tid];
    Lsum[(size_t)b * S + m0 + tid] = __logf(s);
  }
}

// ---- Pass 2 (main): A = exp(QK^T/8 - lsum) stored normalized f32 (direct
// 16B stores, swapped layout) AND X = A.V via shfl-transpose PV. Zero LDS /
// zero fences in the loop; PV MFMAs + V loads fill the store-chain latency
// (R6 fused beat all splits via this overlap; fills prove 6.6 TB/s needs only
// an unstalled issue stream). ~96 regs -> (512,2). ----
__global__ __launch_bounds__(512, 2) void attn_main(
    const _Float16* __restrict__ Qh, const _Float16* __restrict__ Kh,
    const _Float16* __restrict__ Vt, const float* __restrict__ Lsum,
    float* __restrict__ X, float* __restrict__ Aout) {
  const int tid = threadIdx.x;
  const int w = tid >> 6;
  const int l = tid & 63;
  const int l15 = l & 15;
  const int lq = l >> 4;
  const int r4 = lq * 4;
  const int bx = blockIdx.x;
  const int b = bx >> 8;
  const int m0 = (bx & 255) * 16;

  const _Float16* qb = Qh + ((size_t)b * S + m0) * D;
  const _Float16* kb = Kh + ((size_t)b * S) * D;
  const _Float16* vtb = Vt + ((size_t)b * D) * S;

  __shared__ __align__(16) float xred[8][16][66];

  half8 qf0 = *(const half8*)(qb + (size_t)l15 * D + lq * 8);
  half8 qf1 = *(const half8*)(qb + (size_t)l15 * D + 32 + lq * 8);

  const float ls = Lsum[(size_t)b * S + m0 + l15];
  const int nbase = w * 512;
  const int srcA = (lq & 1) * 32 + l15;
  const int srcB = srcA + 16;
  const bool hi = (lq & 2) != 0;

  const _Float16* kp0 = kb + (size_t)(nbase + l15) * D + lq * 8;
  const _Float16* vp0 = vtb + (size_t)l15 * S + nbase + lq * 8;
  float* arow = Aout + ((size_t)(b * S + m0 + l15)) * S + nbase + r4;

  f32x4 xacc[4];
#pragma unroll
  for (int fd = 0; fd < 4; ++fd) xacc[fd] = (f32x4){0.f, 0.f, 0.f, 0.f};

  half8 kc0 = *(const half8*)(kp0);
  half8 kc1 = *(const half8*)(kp0 + 32);

#pragma unroll 1
  for (int s = 0; s < 16; ++s) {
    // independent loads first: V(4) + t1 K pair; K t0 of s+1 prefetched below
    const _Float16* vs = vp0 + s * 32;
    half8 bf0 = *(const half8*)(vs);
    half8 bf1 = *(const half8*)(vs + 16 * S);
    half8 bf2 = *(const half8*)(vs + 32 * S);
    half8 bf3 = *(const half8*)(vs + 48 * S);
    const _Float16* k1p = kp0 + (size_t)(s * 32 + 16) * D;
    half8 k10 = *(const half8*)(k1p);
    half8 k11 = *(const half8*)(k1p + 32);
    half8 kn0 = kc0, kn1 = kc1;
    if (s < 15) {
      const _Float16* knp = kp0 + (size_t)((s + 1) * 32) * D;
      kn0 = *(const half8*)(knp);
      kn1 = *(const half8*)(knp + 32);
    }
    // t0: scores for keys s*32+(0..15) of query l15 (lane: r4..r4+3)
    f32x4 a0 = (f32x4){0.f, 0.f, 0.f, 0.f};
    a0 = __builtin_amdgcn_mfma_f32_16x16x32_f16(kc0, qf0, a0, 0, 0, 0);
    a0 = __builtin_amdgcn_mfma_f32_16x16x32_f16(kc1, qf1, a0, 0, 0, 0);
    f32x4 o0;
#pragma unroll
    for (int j = 0; j < 4; ++j) o0[j] = __expf(a0[j] - ls);  // normalized
    *(f32x4*)(arow + s * 32) = o0;                            // A store (f32)
    half2v h01 = {(_Float16)o0[0], (_Float16)o0[1]};
    half2v h23 = {(_Float16)o0[2], (_Float16)o0[3]};
    int dw0x = __builtin_bit_cast(int, h01);
    int dw0y = __builtin_bit_cast(int, h23);
    // t1: keys s*32+16+(0..15)
    f32x4 a1 = (f32x4){0.f, 0.f, 0.f, 0.f};
    a1 = __builtin_amdgcn_mfma_f32_16x16x32_f16(k10, qf0, a1, 0, 0, 0);
    a1 = __builtin_amdgcn_mfma_f32_16x16x32_f16(k11, qf1, a1, 0, 0, 0);
    f32x4 o1;
#pragma unroll
    for (int j = 0; j < 4; ++j) o1[j] = __expf(a1[j] - ls);
    *(f32x4*)(arow + s * 32 + 16) = o1;
    half2v g01 = {(_Float16)o1[0], (_Float16)o1[1]};
    half2v g23 = {(_Float16)o1[2], (_Float16)o1[3]};
    int dw1x = __builtin_bit_cast(int, g01);
    int dw1y = __builtin_bit_cast(int, g23);
    // shfl transpose -> PV A-frag (numerically proven R8/R9)
    int yA0 = __shfl(dw0x, srcA, 64), yA1 = __shfl(dw0y, srcA, 64);
    int yB0 = __shfl(dw0x, srcB, 64), yB1 = __shfl(dw0y, srcB, 64);
    int xA0 = __shfl(dw1x, srcA, 64), xA1 = __shfl(dw1y, srcA, 64);
    int xB0 = __shfl(dw1x, srcB, 64), xB1 = __shfl(dw1y, srcB, 64);
    int4v ai = {hi ? xA0 : yA0, hi ? xA1 : yA1, hi ? xB0 : yB0, hi ? xB1 : yB1};
    half8 af = __builtin_bit_cast(half8, ai);
    // PV (P already normalized -> X needs no final scale)
    xacc[0] = __builtin_amdgcn_mfma_f32_16x16x32_f16(af, bf0, xacc[0], 0, 0, 0);
    xacc[1] = __builtin_amdgcn_mfma_f32_16x16x32_f16(af, bf1, xacc[1], 0, 0, 0);
    xacc[2] = __builtin_amdgcn_mfma_f32_16x16x32_f16(af, bf2, xacc[2], 0, 0, 0);
    xacc[3] = __builtin_amdgcn_mfma_f32_16x16x32_f16(af, bf3, xacc[3], 0, 0, 0);
    kc0 = kn0;
    kc1 = kn1;
  }

  // cross-wave reduce of X (xacc: X[q=r4+j][d=fd*16+l15])
#pragma unroll
  for (int fd = 0; fd < 4; ++fd)
#pragma unroll
    for (int j = 0; j < 4; ++j)
      xred[w][r4 + j][fd * 16 + l15] = xacc[fd][j];
  __syncthreads();
  float* xrow = X + ((size_t)b * S + m0) * D;
#pragma unroll
  for (int o = tid; o < 16 * 64; o += 512) {
    int r = o >> 6, d = o & 63;
    float s = 0.f;
#pragma unroll
    for (int ww = 0; ww < 8; ++ww) s += xred[ww][r][d];
    xrow[(size_t)r * D + d] = s;
  }
}

extern "C" void kernel_launch(void* const* d_in, const int* in_sizes, int n_in,
                              void* d_out, int out_size, void* d_ws, size_t ws_size,
                              hipStream_t stream) {
  const float* Q = (const float*)d_in[0];
  const float* K = (const float*)d_in[1];
  const float* V = (const float*)d_in[2];
  float* X = (float*)d_out;                       // [16,4096,64]
  float* A = X + (size_t)NB * S * D;              // [16,4096,4096]
  _Float16* Qh = (_Float16*)d_ws;
  _Float16* Kh = Qh + (size_t)NB * S * D;
  _Float16* Vt = Kh + (size_t)NB * S * D;
  float* Lsum = (float*)(Vt + (size_t)NB * S * D);  // [16,4096] f32
  int n = NB * S * D;
  cvt_qk<<<2048, 256, 0, stream>>>(Q, K, Qh, Kh, n);
  cvt_vt<<<NB * 64, 256, 0, stream>>>(V, Vt);
  attn_lsum<<<NB * 256, 512, 0, stream>>>(Qh, Kh, Lsum);
  attn_main<<<NB * 256, 512, 0, stream>>>(Qh, Kh, Vt, Lsum, X, A);
}